// Round 4
// baseline (406.573 us; speedup 1.0000x reference)
//
#include <hip/hip_runtime.h>
#include <hip/hip_bf16.h>
#include <cmath>
#include <cstdint>

namespace {

constexpr int kB = 8;
constexpr int kS = 2048;
constexpr int kD = 1024;
constexpr int kN = kB * kS;          // 16384 rows
constexpr int kChunk = 128;
constexpr int kNChunk = kS / kChunk; // 16
constexpr float kEps = 1e-6f;

typedef __attribute__((ext_vector_type(8))) short bf16x8;
typedef __attribute__((ext_vector_type(4))) float f32x4;

__device__ inline float bf2f(short s) {
  union { unsigned u; float f; } c;
  c.u = ((unsigned)(unsigned short)s) << 16;
  return c.f;
}

struct bh4 { __hip_bfloat16 a, b, c, d; };  // 8-byte bf16 quad

// async global -> LDS, 16B per lane, wave-uniform LDS base
__device__ inline void gload16(const void* g, void* l) {
  __builtin_amdgcn_global_load_lds(
      (const __attribute__((address_space(1))) void*)g,
      (__attribute__((address_space(3))) void*)l, 16, 0, 0);
}

// ---------------- decay vectors ----------------
__global__ void k_decay(float* __restrict__ decay, float* __restrict__ dbeta,
                        float* __restrict__ aL) {
  int h = blockIdx.x * blockDim.x + threadIdx.x;
  if (h >= kD) return;
  float kk = 2.0f + 6.0f * (float)h / (float)(kD - 1);
  float d = exp2f(-1.0f / kk);        // 0.5^(1/k)
  decay[h] = d;
  dbeta[h] = 1.0f - d;
  aL[h] = exp2f(-(float)kChunk / kk); // decay^CHUNK
}

// ---------------- block reduce (sum, sumsq) over 256 threads ---------------
__device__ inline void blockReduce2(float& s1, float& s2) {
#pragma unroll
  for (int off = 32; off > 0; off >>= 1) {
    s1 += __shfl_down(s1, off);
    s2 += __shfl_down(s2, off);
  }
  __shared__ float r1[4], r2[4];
  int wid = threadIdx.x >> 6;
  if ((threadIdx.x & 63) == 0) { r1[wid] = s1; r2[wid] = s2; }
  __syncthreads();
  s1 = r1[0] + r1[1] + r1[2] + r1[3];
  s2 = r2[0] + r2[1] + r2[2] + r2[3];
}

// ---------------- LayerNorm f32 -> bf16 (1 block = 1 row) -----------------
__global__ __launch_bounds__(256) void k_ln_f32in(
    const float* __restrict__ x, const float* __restrict__ w,
    const float* __restrict__ b, __hip_bfloat16* __restrict__ y) {
  int row = blockIdx.x;
  int t = threadIdx.x;
  const float4 v = reinterpret_cast<const float4*>(x + (size_t)row * kD)[t];
  float s1 = v.x + v.y + v.z + v.w;
  float s2 = v.x * v.x + v.y * v.y + v.z * v.z + v.w * v.w;
  blockReduce2(s1, s2);
  float mu = s1 * (1.0f / kD);
  float var = s2 * (1.0f / kD) - mu * mu;
  float rs = rsqrtf(var + kEps);
  float4 wv = reinterpret_cast<const float4*>(w)[t];
  float4 bv = reinterpret_cast<const float4*>(b)[t];
  bh4 o;
  o.a = __float2bfloat16((v.x - mu) * rs * wv.x + bv.x);
  o.b = __float2bfloat16((v.y - mu) * rs * wv.y + bv.y);
  o.c = __float2bfloat16((v.z - mu) * rs * wv.z + bv.z);
  o.d = __float2bfloat16((v.w - mu) * rs * wv.w + bv.w);
  reinterpret_cast<bh4*>(y + (size_t)row * kD)[t] = o;
}

// ---------------- LayerNorm bf16 -> bf16 (1 block = 1 row) ----------------
__global__ __launch_bounds__(256) void k_ln_bf16in(
    const __hip_bfloat16* __restrict__ x, const float* __restrict__ w,
    const float* __restrict__ b, __hip_bfloat16* __restrict__ y) {
  int row = blockIdx.x;
  int t = threadIdx.x;
  short4 q = reinterpret_cast<const short4*>(x + (size_t)row * kD)[t];
  float vv[4] = {bf2f(q.x), bf2f(q.y), bf2f(q.z), bf2f(q.w)};
  float s1 = vv[0] + vv[1] + vv[2] + vv[3];
  float s2 = vv[0] * vv[0] + vv[1] * vv[1] + vv[2] * vv[2] + vv[3] * vv[3];
  blockReduce2(s1, s2);
  float mu = s1 * (1.0f / kD);
  float var = s2 * (1.0f / kD) - mu * mu;
  float rs = rsqrtf(var + kEps);
  float4 wv = reinterpret_cast<const float4*>(w)[t];
  float4 bv = reinterpret_cast<const float4*>(b)[t];
  bh4 o;
  o.a = __float2bfloat16((vv[0] - mu) * rs * wv.x + bv.x);
  o.b = __float2bfloat16((vv[1] - mu) * rs * wv.y + bv.y);
  o.c = __float2bfloat16((vv[2] - mu) * rs * wv.z + bv.z);
  o.d = __float2bfloat16((vv[3] - mu) * rs * wv.w + bv.w);
  reinterpret_cast<bh4*>(y + (size_t)row * kD)[t] = o;
}

// ---------------- weight transpose-cast: W[K][1024] f32 -> WT[1024][K] bf16
__global__ __launch_bounds__(256) void k_transpose_cast(
    const float* __restrict__ W, __hip_bfloat16* __restrict__ WT, int K) {
  __shared__ float tile[32][33];
  int n0 = blockIdx.x * 32, k0 = blockIdx.y * 32;
  int t = threadIdx.x;
  int tr = t >> 3, tc4 = (t & 7) * 4;
  float4 v = *reinterpret_cast<const float4*>(W + (size_t)(k0 + tr) * kD + n0 + tc4);
  tile[tc4 + 0][tr] = v.x;
  tile[tc4 + 1][tr] = v.y;
  tile[tc4 + 2][tr] = v.z;
  tile[tc4 + 3][tr] = v.w;
  __syncthreads();
  bh4 o;
  o.a = __float2bfloat16(tile[tr][tc4 + 0]);
  o.b = __float2bfloat16(tile[tr][tc4 + 1]);
  o.c = __float2bfloat16(tile[tr][tc4 + 2]);
  o.d = __float2bfloat16(tile[tr][tc4 + 3]);
  *reinterpret_cast<bh4*>(WT + (size_t)(n0 + tr) * K + k0 + tc4) = o;
}

// ---------------- bf16 MFMA GEMM, 128x128 tile, BK=32 ---------------------
// T1: bijective XCD-chunk swizzle (1-D grid, nwg % 8 == 0).
// T3/T4: double-buffered LDS, prefetch next K-tile, raw s_barrier + counted
//        s_waitcnt vmcnt(4) so prefetch stays in flight across barriers.
// LDS layout is k-major [kg][row][8] so fragment ds_read_b128 is
// bank-conflict-free (consecutive 8 lanes cover all 8 bank-quads).
__device__ inline void stage_tile(const __hip_bfloat16* __restrict__ Asrc,
                                  int kk, const __hip_bfloat16* __restrict__ BT,
                                  int K, int k0, int bm, int bn, int wid,
                                  int lane, short* Abuf, short* Bbuf) {
#pragma unroll
  for (int c = 0; c < 2; ++c) {
    int chunk = c * 4 + wid;            // 0..7
    int kgc = chunk & 3, half = chunk >> 2;
    int ldso = kgc * 1024 + half * 512 + lane * 8;  // shorts
    int row = half * 64 + lane;
    gload16(Asrc + (size_t)(bm + row) * kD + kk + kgc * 8, Abuf + ldso);
    gload16(BT + (size_t)(bn + row) * K + k0 + kgc * 8, Bbuf + ldso);
  }
}

__global__ __launch_bounds__(256) void k_mfma_gemm(
    const __hip_bfloat16* __restrict__ A1, const __hip_bfloat16* __restrict__ A2,
    const __hip_bfloat16* __restrict__ BT, int K,
    float* __restrict__ C, __hip_bfloat16* __restrict__ Cb,
    const float* __restrict__ colscale, const float* __restrict__ bias) {
  __shared__ short As[2][4096];
  __shared__ short Bs[2][4096];
  const int t = threadIdx.x;
  const int wid = t >> 6, lane = t & 63;
  // XCD swizzle (nwg % 8 == 0): bid%8 = XCD -> give it a contiguous chunk
  const int nwg = gridDim.x;
  const int bid = blockIdx.x;
  const int s = (bid & 7) * (nwg >> 3) + (bid >> 3);
  const int bn = (s & 7) * 128;        // 8 column blocks (kD/128)
  const int bm = (s >> 3) * 128;
  const int wr = wid >> 1, wc = wid & 1;  // wave -> 64x64 quadrant
  const int r = lane & 15, kg = lane >> 4;

  f32x4 acc[4][4];
#pragma unroll
  for (int m = 0; m < 4; ++m)
#pragma unroll
    for (int n = 0; n < 4; ++n) acc[m][n] = (f32x4){0.f, 0.f, 0.f, 0.f};

  const int NT = K / 32;
  // tile-t operand select (concat A when A2 != null)
  const __hip_bfloat16* Asrc0;
  int kk0;
  {
    Asrc0 = A1; kk0 = 0;
  }
  stage_tile(Asrc0, kk0, BT, K, 0, bm, bn, wid, lane, As[0], Bs[0]);

  for (int tt = 0; tt < NT; ++tt) {
    const int cur = tt & 1;
    if (tt + 1 < NT) {
      int k0n = (tt + 1) * 32;
      const __hip_bfloat16* Asrc;
      int kk;
      if (A2 && k0n >= kD) { Asrc = A2; kk = k0n - kD; }
      else                 { Asrc = A1; kk = k0n; }
      stage_tile(Asrc, kk, BT, K, k0n, bm, bn, wid, lane, As[cur ^ 1],
                 Bs[cur ^ 1]);
      asm volatile("s_waitcnt vmcnt(4)" ::: "memory");  // tile tt landed (own)
    } else {
      asm volatile("s_waitcnt vmcnt(0)" ::: "memory");
    }
    __builtin_amdgcn_s_barrier();      // all waves' tile-tt loads landed
    asm volatile("" ::: "memory");     // keep LDS reads below the barrier
    bf16x8 af[4], bf[4];
#pragma unroll
    for (int m = 0; m < 4; ++m)
      af[m] = *reinterpret_cast<const bf16x8*>(
          &As[cur][kg * 1024 + (wr * 64 + m * 16 + r) * 8]);
#pragma unroll
    for (int n = 0; n < 4; ++n)
      bf[n] = *reinterpret_cast<const bf16x8*>(
          &Bs[cur][kg * 1024 + (wc * 64 + n * 16 + r) * 8]);
#pragma unroll
    for (int m = 0; m < 4; ++m)
#pragma unroll
      for (int n = 0; n < 4; ++n)
        acc[m][n] = __builtin_amdgcn_mfma_f32_16x16x32_bf16(af[m], bf[n],
                                                            acc[m][n], 0, 0, 0);
    __builtin_amdgcn_sched_barrier(0);  // pin reads+MFMA above the barrier
    __builtin_amdgcn_s_barrier();       // all waves done reading buf[cur]
  }

  // epilogue: D[row = kg*4+j][col = r] per fragment (m89-verified mapping)
  int col[4];
  float cs[4], bi[4];
#pragma unroll
  for (int n = 0; n < 4; ++n) {
    col[n] = bn + wc * 64 + n * 16 + r;
    cs[n] = colscale ? colscale[col[n]] : 1.0f;
    bi[n] = bias ? bias[col[n]] : 0.0f;
  }
#pragma unroll
  for (int m = 0; m < 4; ++m) {
#pragma unroll
    for (int j = 0; j < 4; ++j) {
      int row = bm + wr * 64 + m * 16 + kg * 4 + j;
#pragma unroll
      for (int n = 0; n < 4; ++n) {
        float v = acc[m][n][j] * cs[n] + bi[n];
        if (C) C[(size_t)row * kD + col[n]] = v;
        if (Cb) Cb[(size_t)row * kD + col[n]] = __float2bfloat16(v);
      }
    }
  }
}

// ---------------- chunked scan, phase 1: per-chunk end values (bf16 in) ---
__global__ __launch_bounds__(256) void k_scan_ends(
    const __hip_bfloat16* __restrict__ u, const float* __restrict__ decay,
    float* __restrict__ ends) {
  int tid = blockIdx.x * blockDim.x + threadIdx.x;  // [0, B*NCHUNK*D)
  int h = tid & (kD - 1);
  int c = (tid >> 10) & (kNChunk - 1);
  int b = tid >> 14;
  float a = decay[h];
  const __hip_bfloat16* up =
      u + ((size_t)(b * kS) + (size_t)c * kChunk) * kD + h;
  float v = 0.f;
#pragma unroll 8
  for (int i = 0; i < kChunk; ++i)
    v = fmaf(a, v, bf2f(*(const short*)(up + (size_t)i * kD)));
  ends[tid] = v;
}

// ---------------- phase 2: scan carries across chunks ---------------------
__global__ __launch_bounds__(256) void k_scan_carry(
    const float* __restrict__ ends, const float* __restrict__ aL,
    float* __restrict__ carry) {
  int tid = blockIdx.x * blockDim.x + threadIdx.x;  // [0, B*D)
  int h = tid & (kD - 1);
  int b = tid >> 10;
  float al = aL[h];
  float car = 0.f;
#pragma unroll
  for (int c = 0; c < kNChunk; ++c) {
    size_t idx = ((size_t)(b * kNChunk + c)) * kD + h;
    carry[idx] = car;
    car = fmaf(al, car, ends[idx]);
  }
}

// ---------------- phase 3: rescan with carry, in-place u -> cx (bf16) -----
__global__ __launch_bounds__(256) void k_scan_apply(
    __hip_bfloat16* __restrict__ u, const float* __restrict__ decay,
    const float* __restrict__ carry) {
  int tid = blockIdx.x * blockDim.x + threadIdx.x;
  int h = tid & (kD - 1);
  int c = (tid >> 10) & (kNChunk - 1);
  int b = tid >> 14;
  float a = decay[h];
  float v = carry[tid];
  __hip_bfloat16* up = u + ((size_t)(b * kS) + (size_t)c * kChunk) * kD + h;
#pragma unroll 8
  for (int i = 0; i < kChunk; ++i) {
    v = fmaf(a, v, bf2f(*(const short*)(up + (size_t)i * kD)));
    up[(size_t)i * kD] = __float2bfloat16(v);
  }
}

// ---------------- final: LN(gpre) -> sigmoid -> blend ---------------------
__global__ __launch_bounds__(256) void k_final(
    const __hip_bfloat16* __restrict__ gpre, const __hip_bfloat16* __restrict__ res,
    const __hip_bfloat16* __restrict__ outp, const float* __restrict__ w,
    const float* __restrict__ b, float* __restrict__ y) {
  int row = blockIdx.x;
  int t = threadIdx.x;
  short4 q = reinterpret_cast<const short4*>(gpre + (size_t)row * kD)[t];
  float vv[4] = {bf2f(q.x), bf2f(q.y), bf2f(q.z), bf2f(q.w)};
  float s1 = vv[0] + vv[1] + vv[2] + vv[3];
  float s2 = vv[0] * vv[0] + vv[1] * vv[1] + vv[2] * vv[2] + vv[3] * vv[3];
  blockReduce2(s1, s2);
  float mu = s1 * (1.0f / kD);
  float var = s2 * (1.0f / kD) - mu * mu;
  float rs = rsqrtf(var + kEps);
  float4 wv = reinterpret_cast<const float4*>(w)[t];
  float4 bv = reinterpret_cast<const float4*>(b)[t];
  short4 r4 = reinterpret_cast<const short4*>(res + (size_t)row * kD)[t];
  short4 o4 = reinterpret_cast<const short4*>(outp + (size_t)row * kD)[t];
  float rr[4] = {bf2f(r4.x), bf2f(r4.y), bf2f(r4.z), bf2f(r4.w)};
  float oo[4] = {bf2f(o4.x), bf2f(o4.y), bf2f(o4.z), bf2f(o4.w)};
  float ww[4] = {wv.x, wv.y, wv.z, wv.w};
  float bb[4] = {bv.x, bv.y, bv.z, bv.w};
  float4 out;
  float* op = &out.x;
#pragma unroll
  for (int i = 0; i < 4; ++i) {
    float z = (vv[i] - mu) * rs * ww[i] + bb[i];
    float g = 1.0f / (1.0f + expf(-z));
    op[i] = rr[i] + g * (oo[i] - rr[i]);
  }
  reinterpret_cast<float4*>(y + (size_t)row * kD)[t] = out;
}

}  // namespace

extern "C" void kernel_launch(void* const* d_in, const int* in_sizes, int n_in,
                              void* d_out, int out_size, void* d_ws,
                              size_t ws_size, hipStream_t stream) {
  const float* x = (const float*)d_in[0];
  const float* Wt = (const float*)d_in[1];
  const float* Wo = (const float*)d_in[2];
  const float* Wg = (const float*)d_in[3];
  const float* bg = (const float*)d_in[4];
  const float* ln1w = (const float*)d_in[5];
  const float* ln1b = (const float*)d_in[6];
  const float* lncw = (const float*)d_in[7];
  const float* lncb = (const float*)d_in[8];
  const float* lngw = (const float*)d_in[9];
  const float* lngb = (const float*)d_in[10];
  float* y = (float*)d_out;

  char* ws = (char*)d_ws;
  size_t off = 0;
  auto alloc = [&](size_t bytes) {
    char* p = ws + off;
    off += (bytes + 255) & ~(size_t)255;
    return p;
  };
  __hip_bfloat16* xnb = (__hip_bfloat16*)alloc((size_t)kN * kD * 2);  // _x (res)
  __hip_bfloat16* ub = (__hip_bfloat16*)alloc((size_t)kN * kD * 2);   // u -> cx -> gpre
  __hip_bfloat16* outb = (__hip_bfloat16*)alloc((size_t)kN * kD * 2); // out
  __hip_bfloat16* cxn = (__hip_bfloat16*)alloc((size_t)kN * kD * 2);  // LN(cx)
  __hip_bfloat16* WtT = (__hip_bfloat16*)alloc((size_t)kD * kD * 2);
  __hip_bfloat16* WoT = (__hip_bfloat16*)alloc((size_t)kD * kD * 2);
  __hip_bfloat16* WgT = (__hip_bfloat16*)alloc((size_t)kD * 2 * kD * 2);
  float* decay = (float*)alloc(kD * 4);
  float* dbeta = (float*)alloc(kD * 4);
  float* aL = (float*)alloc(kD * 4);
  float* ends = (float*)alloc((size_t)kB * kNChunk * kD * 4);
  float* carry = (float*)alloc((size_t)kB * kNChunk * kD * 4);

  const int nwg = (kD / 128) * (kN / 128);  // 8 * 128 = 1024, % 8 == 0

  k_decay<<<(kD + 255) / 256, 256, 0, stream>>>(decay, dbeta, aL);
  // weight transpose-casts (f32 [K][N] -> bf16 [N][K])
  k_transpose_cast<<<dim3(kD / 32, kD / 32), 256, 0, stream>>>(Wt, WtT, kD);
  k_transpose_cast<<<dim3(kD / 32, kD / 32), 256, 0, stream>>>(Wo, WoT, kD);
  k_transpose_cast<<<dim3(kD / 32, 2 * kD / 32), 256, 0, stream>>>(Wg, WgT, 2 * kD);
  // _x = LN(x) -> bf16
  k_ln_f32in<<<kN, 256, 0, stream>>>(x, ln1w, ln1b, xnb);
  // u = (_x @ Wt) * decay_beta   (bf16 out)
  k_mfma_gemm<<<nwg, 256, 0, stream>>>(xnb, nullptr, WtT, kD, nullptr, ub,
                                       dbeta, nullptr);
  // chunked scan: u -> cx (in place, bf16 storage, f32 accumulate)
  k_scan_ends<<<(kB * kNChunk * kD) / 256, 256, 0, stream>>>(ub, decay, ends);
  k_scan_carry<<<(kB * kD) / 256, 256, 0, stream>>>(ends, aL, carry);
  k_scan_apply<<<(kB * kNChunk * kD) / 256, 256, 0, stream>>>(ub, decay, carry);
  // cxn = LN(cx) -> bf16
  k_ln_bf16in<<<kN, 256, 0, stream>>>(ub, lncw, lncb, cxn);
  // out = LN(cx) @ Wo  (bf16 out)
  k_mfma_gemm<<<nwg, 256, 0, stream>>>(cxn, nullptr, WoT, kD, nullptr, outb,
                                       nullptr, nullptr);
  // gpre = concat(_x, out) @ Wg + bg  (bf16 out, overwrites ub; cx dead)
  k_mfma_gemm<<<nwg, 256, 0, stream>>>(xnb, outb, WgT, 2 * kD, nullptr, ub,
                                       nullptr, bg);
  // y = res + sigmoid(LN(gpre)) * (out - res)
  k_final<<<kN, 256, 0, stream>>>(ub, xnb, outb, lngw, lngb, y);
}

// Round 5
// 281.175 us; speedup vs baseline: 1.4460x; 1.4460x over previous
//
#include <hip/hip_runtime.h>
#include <hip/hip_bf16.h>
#include <cmath>
#include <cstdint>

namespace {

constexpr int kB = 8;
constexpr int kS = 2048;
constexpr int kD = 1024;
constexpr int kN = kB * kS;          // 16384 rows
constexpr int kChunk = 128;
constexpr int kNChunk = kS / kChunk; // 16
constexpr float kEps = 1e-6f;

typedef __attribute__((ext_vector_type(8))) short bf16x8;
typedef __attribute__((ext_vector_type(4))) float f32x4;

__device__ inline float bf2f(short s) {
  union { unsigned u; float f; } c;
  c.u = ((unsigned)(unsigned short)s) << 16;
  return c.f;
}

struct bh4 { __hip_bfloat16 a, b, c, d; };  // 8-byte bf16 quad

// async global -> LDS, 16B per lane, wave-uniform LDS base (+lane*16)
__device__ inline void gload16(const void* g, void* l) {
  __builtin_amdgcn_global_load_lds(
      (const __attribute__((address_space(1))) void*)g,
      (__attribute__((address_space(3))) void*)l, 16, 0, 0);
}

// ---------------- decay vectors ----------------
__global__ void k_decay(float* __restrict__ decay, float* __restrict__ dbeta,
                        float* __restrict__ aL) {
  int h = blockIdx.x * blockDim.x + threadIdx.x;
  if (h >= kD) return;
  float kk = 2.0f + 6.0f * (float)h / (float)(kD - 1);
  float d = exp2f(-1.0f / kk);        // 0.5^(1/k)
  decay[h] = d;
  dbeta[h] = 1.0f - d;
  aL[h] = exp2f(-(float)kChunk / kk); // decay^CHUNK
}

// ---------------- block reduce (sum, sumsq) over 256 threads ---------------
__device__ inline void blockReduce2(float& s1, float& s2) {
#pragma unroll
  for (int off = 32; off > 0; off >>= 1) {
    s1 += __shfl_down(s1, off);
    s2 += __shfl_down(s2, off);
  }
  __shared__ float r1[4], r2[4];
  int wid = threadIdx.x >> 6;
  if ((threadIdx.x & 63) == 0) { r1[wid] = s1; r2[wid] = s2; }
  __syncthreads();
  s1 = r1[0] + r1[1] + r1[2] + r1[3];
  s2 = r2[0] + r2[1] + r2[2] + r2[3];
}

// ---------------- LayerNorm f32 -> bf16 (1 block = 1 row) -----------------
__global__ __launch_bounds__(256) void k_ln_f32in(
    const float* __restrict__ x, const float* __restrict__ w,
    const float* __restrict__ b, __hip_bfloat16* __restrict__ y) {
  int row = blockIdx.x;
  int t = threadIdx.x;
  const float4 v = reinterpret_cast<const float4*>(x + (size_t)row * kD)[t];
  float s1 = v.x + v.y + v.z + v.w;
  float s2 = v.x * v.x + v.y * v.y + v.z * v.z + v.w * v.w;
  blockReduce2(s1, s2);
  float mu = s1 * (1.0f / kD);
  float var = s2 * (1.0f / kD) - mu * mu;
  float rs = rsqrtf(var + kEps);
  float4 wv = reinterpret_cast<const float4*>(w)[t];
  float4 bv = reinterpret_cast<const float4*>(b)[t];
  bh4 o;
  o.a = __float2bfloat16((v.x - mu) * rs * wv.x + bv.x);
  o.b = __float2bfloat16((v.y - mu) * rs * wv.y + bv.y);
  o.c = __float2bfloat16((v.z - mu) * rs * wv.z + bv.z);
  o.d = __float2bfloat16((v.w - mu) * rs * wv.w + bv.w);
  reinterpret_cast<bh4*>(y + (size_t)row * kD)[t] = o;
}

// ---------------- LayerNorm bf16 -> bf16 (1 block = 1 row) ----------------
__global__ __launch_bounds__(256) void k_ln_bf16in(
    const __hip_bfloat16* __restrict__ x, const float* __restrict__ w,
    const float* __restrict__ b, __hip_bfloat16* __restrict__ y) {
  int row = blockIdx.x;
  int t = threadIdx.x;
  short4 q = reinterpret_cast<const short4*>(x + (size_t)row * kD)[t];
  float vv[4] = {bf2f(q.x), bf2f(q.y), bf2f(q.z), bf2f(q.w)};
  float s1 = vv[0] + vv[1] + vv[2] + vv[3];
  float s2 = vv[0] * vv[0] + vv[1] * vv[1] + vv[2] * vv[2] + vv[3] * vv[3];
  blockReduce2(s1, s2);
  float mu = s1 * (1.0f / kD);
  float var = s2 * (1.0f / kD) - mu * mu;
  float rs = rsqrtf(var + kEps);
  float4 wv = reinterpret_cast<const float4*>(w)[t];
  float4 bv = reinterpret_cast<const float4*>(b)[t];
  bh4 o;
  o.a = __float2bfloat16((vv[0] - mu) * rs * wv.x + bv.x);
  o.b = __float2bfloat16((vv[1] - mu) * rs * wv.y + bv.y);
  o.c = __float2bfloat16((vv[2] - mu) * rs * wv.z + bv.z);
  o.d = __float2bfloat16((vv[3] - mu) * rs * wv.w + bv.w);
  reinterpret_cast<bh4*>(y + (size_t)row * kD)[t] = o;
}

// ---------------- weight transpose-cast: W[K][1024] f32 -> WT[1024][K] bf16
__global__ __launch_bounds__(256) void k_transpose_cast(
    const float* __restrict__ W, __hip_bfloat16* __restrict__ WT, int K) {
  __shared__ float tile[32][33];
  int n0 = blockIdx.x * 32, k0 = blockIdx.y * 32;
  int t = threadIdx.x;
  int tr = t >> 3, tc4 = (t & 7) * 4;
  float4 v = *reinterpret_cast<const float4*>(W + (size_t)(k0 + tr) * kD + n0 + tc4);
  tile[tc4 + 0][tr] = v.x;
  tile[tc4 + 1][tr] = v.y;
  tile[tc4 + 2][tr] = v.z;
  tile[tc4 + 3][tr] = v.w;
  __syncthreads();
  bh4 o;
  o.a = __float2bfloat16(tile[tr][tc4 + 0]);
  o.b = __float2bfloat16(tile[tr][tc4 + 1]);
  o.c = __float2bfloat16(tile[tr][tc4 + 2]);
  o.d = __float2bfloat16(tile[tr][tc4 + 3]);
  *reinterpret_cast<bh4*>(WT + (size_t)(n0 + tr) * K + k0 + tc4) = o;
}

// ---------------- bf16 MFMA GEMM, 256x256 tile, BK=64, 8 waves ------------
// Phase-pipelined schedule (T3+T4): 4 phases per K-tile, each phase =
// {ds_read subtile, 1 half-tile stage issue (2x global_load_lds), barrier,
//  lgkmcnt(0)+sched_barrier, setprio(1) 16 MFMA setprio(0), barrier}.
// Counted vmcnt(4) only at phase 3 (never 0 in steady state) -> stage loads
// stay in flight across barriers. LDS layout k-major [kgrp8][row128][8bf16]
// per half-tile: conflict-free ds_read_b128 (round-4 measured 0 conflicts)
// and linear for global_load_lds. Race-freedom: slot X staged at phase p'
// only if X's last ds_read was in phase p < p' (reads drained by lgkmcnt(0)
// before p's closing barrier). Stage map per tile T: q0/q1 -> A halves of
// T+1 (last read T-1.P3); q2/q3 -> B halves of T+2 into current buf (B last
// read at this tile's P0; held in regs after).
__global__ __launch_bounds__(512, 2) void k_mfma_gemm(
    const __hip_bfloat16* __restrict__ A1, const __hip_bfloat16* __restrict__ A2,
    const __hip_bfloat16* __restrict__ BT, int K,
    float* __restrict__ C, __hip_bfloat16* __restrict__ Cb,
    const float* __restrict__ colscale, const float* __restrict__ bias) {
  __shared__ short As[2][2][8192];  // [dbuf][half][kgrp*1024 + rh*512 + ...]
  __shared__ short Bs[2][2][8192];
  const int t = threadIdx.x;
  const int wid = t >> 6, lane = t & 63;
  // bijective XCD swizzle (nwg == 256, % 8 == 0)
  const int nwg = gridDim.x;
  const int bid = blockIdx.x;
  const int s = (bid & 7) * (nwg >> 3) + (bid >> 3);
  const int bn = (s & 3) * 256;   // 4 column tiles (kD/256)
  const int bm = (s >> 2) * 256;
  const int wr = wid >> 2;        // 0..1  (M dir; owns A half wr)
  const int wcn = wid & 3;        // 0..3  (N dir; owns B half wcn>>1)
  const int r = lane & 15, kg = lane >> 4;
  const int NT = K / 64;

  // stage one half-tile (128 rows x 64 k): wave wid covers kgrp=wid, both
  // row-halves. LDS dest = uniform base + lane*16B (linear); global src is
  // per-lane.
  auto stageA = [&](int kt, int h) {
    const __hip_bfloat16* Asrc = A1;
    int kk = kt * 64;
    if (A2 && kk >= kD) { Asrc = A2; kk -= kD; }
    short* dst = &As[kt & 1][h][0];
#pragma unroll
    for (int j = 0; j < 2; ++j) {
      int row = j * 64 + lane;
      gload16(Asrc + (size_t)(bm + h * 128 + row) * kD + kk + wid * 8,
              dst + wid * 1024 + j * 512 + lane * 8);
    }
  };
  auto stageB = [&](int kt, int h) {
    short* dst = &Bs[kt & 1][h][0];
#pragma unroll
    for (int j = 0; j < 2; ++j) {
      int row = j * 64 + lane;
      gload16(BT + (size_t)(bn + h * 128 + row) * K + kt * 64 + wid * 8,
              dst + wid * 1024 + j * 512 + lane * 8);
    }
  };

  f32x4 acc[8][4];
#pragma unroll
  for (int m = 0; m < 8; ++m)
#pragma unroll
    for (int n = 0; n < 4; ++n) acc[m][n] = (f32x4){0.f, 0.f, 0.f, 0.f};

  // prologue: tile 0 fully + B halves of tile 1 (12 loads/wave)
  stageA(0, 0); stageA(0, 1); stageB(0, 0); stageB(0, 1);
  stageB(1, 0); stageB(1, 1);
  asm volatile("s_waitcnt vmcnt(4)" ::: "memory");  // tile 0 landed
  __builtin_amdgcn_s_barrier();

  bf16x8 bfr[4][2];  // B fragments held across a tile's 4 phases
  for (int T = 0; T < NT; ++T) {
    const int bc = T & 1;
    const short* Ab = &As[bc][wr][0];
    const short* Bb = &Bs[bc][wcn >> 1][0];
    const int bcol = (wcn & 1) * 64;
#pragma unroll
    for (int q = 0; q < 4; ++q) {
      bf16x8 a[2][2];  // [mm][ksub]
#pragma unroll
      for (int mm = 0; mm < 2; ++mm)
#pragma unroll
        for (int ks = 0; ks < 2; ++ks)
          a[mm][ks] = *reinterpret_cast<const bf16x8*>(
              Ab + (ks * 4 + kg) * 1024 + ((2 * q + mm) * 16 + r) * 8);
      if (q == 0) {
#pragma unroll
        for (int n = 0; n < 4; ++n)
#pragma unroll
          for (int ks = 0; ks < 2; ++ks)
            bfr[n][ks] = *reinterpret_cast<const bf16x8*>(
                Bb + (ks * 4 + kg) * 1024 + (bcol + n * 16 + r) * 8);
      }
      // stage issues (see race-freedom note above)
      if (q == 0 && T + 1 < NT) stageA(T + 1, 0);
      if (q == 1 && T + 1 < NT) stageA(T + 1, 1);
      if (q == 2 && T + 2 < NT) stageB(T + 2, 0);
      if (q == 3 && T + 2 < NT) stageB(T + 2, 1);
      __builtin_amdgcn_s_barrier();
      asm volatile("s_waitcnt lgkmcnt(0)" ::: "memory");
      __builtin_amdgcn_sched_barrier(0);  // rule #18: pin MFMA below wait
      __builtin_amdgcn_s_setprio(1);
#pragma unroll
      for (int mm = 0; mm < 2; ++mm)
#pragma unroll
        for (int n = 0; n < 4; ++n)
#pragma unroll
          for (int ks = 0; ks < 2; ++ks)
            acc[2 * q + mm][n] = __builtin_amdgcn_mfma_f32_16x16x32_bf16(
                a[mm][ks], bfr[n][ks], acc[2 * q + mm][n], 0, 0, 0);
      __builtin_amdgcn_s_setprio(0);
      if (q == 3 && T + 1 < NT) {
        if (T + 2 < NT)
          asm volatile("s_waitcnt vmcnt(4)" ::: "memory");  // T+1 landed
        else
          asm volatile("s_waitcnt vmcnt(0)" ::: "memory");
      }
      __builtin_amdgcn_s_barrier();
    }
  }

  // epilogue: D[row = kg*4+j][col = r] per fragment (m89-verified mapping)
  int col[4];
  float cs[4], bi[4];
#pragma unroll
  for (int n = 0; n < 4; ++n) {
    col[n] = bn + wcn * 64 + n * 16 + r;
    cs[n] = colscale ? colscale[col[n]] : 1.0f;
    bi[n] = bias ? bias[col[n]] : 0.0f;
  }
#pragma unroll
  for (int m = 0; m < 8; ++m) {
#pragma unroll
    for (int j = 0; j < 4; ++j) {
      int row = bm + wr * 128 + m * 16 + kg * 4 + j;
#pragma unroll
      for (int n = 0; n < 4; ++n) {
        float v = acc[m][n][j] * cs[n] + bi[n];
        if (C) C[(size_t)row * kD + col[n]] = v;
        if (Cb) Cb[(size_t)row * kD + col[n]] = __float2bfloat16(v);
      }
    }
  }
}

// ---------------- chunked scan, phase 1: per-chunk end values (bf16 in) ---
__global__ __launch_bounds__(256) void k_scan_ends(
    const __hip_bfloat16* __restrict__ u, const float* __restrict__ decay,
    float* __restrict__ ends) {
  int tid = blockIdx.x * blockDim.x + threadIdx.x;  // [0, B*NCHUNK*D)
  int h = tid & (kD - 1);
  int c = (tid >> 10) & (kNChunk - 1);
  int b = tid >> 14;
  float a = decay[h];
  const __hip_bfloat16* up =
      u + ((size_t)(b * kS) + (size_t)c * kChunk) * kD + h;
  float v = 0.f;
#pragma unroll 8
  for (int i = 0; i < kChunk; ++i)
    v = fmaf(a, v, bf2f(*(const short*)(up + (size_t)i * kD)));
  ends[tid] = v;
}

// ---------------- phase 2: scan carries across chunks ---------------------
__global__ __launch_bounds__(256) void k_scan_carry(
    const float* __restrict__ ends, const float* __restrict__ aL,
    float* __restrict__ carry) {
  int tid = blockIdx.x * blockDim.x + threadIdx.x;  // [0, B*D)
  int h = tid & (kD - 1);
  int b = tid >> 10;
  float al = aL[h];
  float car = 0.f;
#pragma unroll
  for (int c = 0; c < kNChunk; ++c) {
    size_t idx = ((size_t)(b * kNChunk + c)) * kD + h;
    carry[idx] = car;
    car = fmaf(al, car, ends[idx]);
  }
}

// ---------------- phase 3: rescan with carry, in-place u -> cx (bf16) -----
__global__ __launch_bounds__(256) void k_scan_apply(
    __hip_bfloat16* __restrict__ u, const float* __restrict__ decay,
    const float* __restrict__ carry) {
  int tid = blockIdx.x * blockDim.x + threadIdx.x;
  int h = tid & (kD - 1);
  int c = (tid >> 10) & (kNChunk - 1);
  int b = tid >> 14;
  float a = decay[h];
  float v = carry[tid];
  __hip_bfloat16* up = u + ((size_t)(b * kS) + (size_t)c * kChunk) * kD + h;
#pragma unroll 8
  for (int i = 0; i < kChunk; ++i) {
    v = fmaf(a, v, bf2f(*(const short*)(up + (size_t)i * kD)));
    up[(size_t)i * kD] = __float2bfloat16(v);
  }
}

// ---------------- final: LN(gpre) -> sigmoid -> blend ---------------------
__global__ __launch_bounds__(256) void k_final(
    const __hip_bfloat16* __restrict__ gpre, const __hip_bfloat16* __restrict__ res,
    const __hip_bfloat16* __restrict__ outp, const float* __restrict__ w,
    const float* __restrict__ b, float* __restrict__ y) {
  int row = blockIdx.x;
  int t = threadIdx.x;
  short4 q = reinterpret_cast<const short4*>(gpre + (size_t)row * kD)[t];
  float vv[4] = {bf2f(q.x), bf2f(q.y), bf2f(q.z), bf2f(q.w)};
  float s1 = vv[0] + vv[1] + vv[2] + vv[3];
  float s2 = vv[0] * vv[0] + vv[1] * vv[1] + vv[2] * vv[2] + vv[3] * vv[3];
  blockReduce2(s1, s2);
  float mu = s1 * (1.0f / kD);
  float var = s2 * (1.0f / kD) - mu * mu;
  float rs = rsqrtf(var + kEps);
  float4 wv = reinterpret_cast<const float4*>(w)[t];
  float4 bv = reinterpret_cast<const float4*>(b)[t];
  short4 r4 = reinterpret_cast<const short4*>(res + (size_t)row * kD)[t];
  short4 o4 = reinterpret_cast<const short4*>(outp + (size_t)row * kD)[t];
  float rr[4] = {bf2f(r4.x), bf2f(r4.y), bf2f(r4.z), bf2f(r4.w)};
  float oo[4] = {bf2f(o4.x), bf2f(o4.y), bf2f(o4.z), bf2f(o4.w)};
  float ww[4] = {wv.x, wv.y, wv.z, wv.w};
  float bb[4] = {bv.x, bv.y, bv.z, bv.w};
  float4 out;
  float* op = &out.x;
#pragma unroll
  for (int i = 0; i < 4; ++i) {
    float z = (vv[i] - mu) * rs * ww[i] + bb[i];
    float g = 1.0f / (1.0f + expf(-z));
    op[i] = rr[i] + g * (oo[i] - rr[i]);
  }
  reinterpret_cast<float4*>(y + (size_t)row * kD)[t] = out;
}

}  // namespace

extern "C" void kernel_launch(void* const* d_in, const int* in_sizes, int n_in,
                              void* d_out, int out_size, void* d_ws,
                              size_t ws_size, hipStream_t stream) {
  const float* x = (const float*)d_in[0];
  const float* Wt = (const float*)d_in[1];
  const float* Wo = (const float*)d_in[2];
  const float* Wg = (const float*)d_in[3];
  const float* bg = (const float*)d_in[4];
  const float* ln1w = (const float*)d_in[5];
  const float* ln1b = (const float*)d_in[6];
  const float* lncw = (const float*)d_in[7];
  const float* lncb = (const float*)d_in[8];
  const float* lngw = (const float*)d_in[9];
  const float* lngb = (const float*)d_in[10];
  float* y = (float*)d_out;

  char* ws = (char*)d_ws;
  size_t off = 0;
  auto alloc = [&](size_t bytes) {
    char* p = ws + off;
    off += (bytes + 255) & ~(size_t)255;
    return p;
  };
  __hip_bfloat16* xnb = (__hip_bfloat16*)alloc((size_t)kN * kD * 2);  // _x (res)
  __hip_bfloat16* ub = (__hip_bfloat16*)alloc((size_t)kN * kD * 2);   // u -> cx -> gpre
  __hip_bfloat16* outb = (__hip_bfloat16*)alloc((size_t)kN * kD * 2); // out
  __hip_bfloat16* cxn = (__hip_bfloat16*)alloc((size_t)kN * kD * 2);  // LN(cx)
  __hip_bfloat16* WtT = (__hip_bfloat16*)alloc((size_t)kD * kD * 2);
  __hip_bfloat16* WoT = (__hip_bfloat16*)alloc((size_t)kD * kD * 2);
  __hip_bfloat16* WgT = (__hip_bfloat16*)alloc((size_t)kD * 2 * kD * 2);
  float* decay = (float*)alloc(kD * 4);
  float* dbeta = (float*)alloc(kD * 4);
  float* aL = (float*)alloc(kD * 4);
  float* ends = (float*)alloc((size_t)kB * kNChunk * kD * 4);
  float* carry = (float*)alloc((size_t)kB * kNChunk * kD * 4);

  const int nwg = (kD / 256) * (kN / 256);  // 4 * 64 = 256, % 8 == 0

  k_decay<<<(kD + 255) / 256, 256, 0, stream>>>(decay, dbeta, aL);
  // weight transpose-casts (f32 [K][N] -> bf16 [N][K])
  k_transpose_cast<<<dim3(kD / 32, kD / 32), 256, 0, stream>>>(Wt, WtT, kD);
  k_transpose_cast<<<dim3(kD / 32, kD / 32), 256, 0, stream>>>(Wo, WoT, kD);
  k_transpose_cast<<<dim3(kD / 32, 2 * kD / 32), 256, 0, stream>>>(Wg, WgT, 2 * kD);
  // _x = LN(x) -> bf16
  k_ln_f32in<<<kN, 256, 0, stream>>>(x, ln1w, ln1b, xnb);
  // u = (_x @ Wt) * decay_beta   (bf16 out)
  k_mfma_gemm<<<nwg, 512, 0, stream>>>(xnb, nullptr, WtT, kD, nullptr, ub,
                                       dbeta, nullptr);
  // chunked scan: u -> cx (in place, bf16 storage, f32 accumulate)
  k_scan_ends<<<(kB * kNChunk * kD) / 256, 256, 0, stream>>>(ub, decay, ends);
  k_scan_carry<<<(kB * kD) / 256, 256, 0, stream>>>(ends, aL, carry);
  k_scan_apply<<<(kB * kNChunk * kD) / 256, 256, 0, stream>>>(ub, decay, carry);
  // cxn = LN(cx) -> bf16
  k_ln_bf16in<<<kN, 256, 0, stream>>>(ub, lncw, lncb, cxn);
  // out = LN(cx) @ Wo  (bf16 out)
  k_mfma_gemm<<<nwg, 512, 0, stream>>>(cxn, nullptr, WoT, kD, nullptr, outb,
                                       nullptr, nullptr);
  // gpre = concat(_x, out) @ Wg + bg  (bf16 out, overwrites ub; cx dead)
  k_mfma_gemm<<<nwg, 512, 0, stream>>>(xnb, outb, WgT, 2 * kD, nullptr, ub,
                                       nullptr, bg);
  // y = res + sigmoid(LN(gpre)) * (out - res)
  k_final<<<kN, 256, 0, stream>>>(ub, xnb, outb, lngw, lngb, y);
}

// Round 6
// 278.352 us; speedup vs baseline: 1.4606x; 1.0101x over previous
//
#include <hip/hip_runtime.h>
#include <hip/hip_bf16.h>
#include <cmath>
#include <cstdint>

namespace {

constexpr int kB = 8;
constexpr int kS = 2048;
constexpr int kD = 1024;
constexpr int kN = kB * kS;          // 16384 rows
constexpr int kChunk = 128;
constexpr int kNChunk = kS / kChunk; // 16
constexpr float kEps = 1e-6f;

typedef __attribute__((ext_vector_type(8))) short bf16x8;
typedef __attribute__((ext_vector_type(4))) float f32x4;

__device__ inline float bf2f(short s) {
  union { unsigned u; float f; } c;
  c.u = ((unsigned)(unsigned short)s) << 16;
  return c.f;
}

struct bh4 { __hip_bfloat16 a, b, c, d; };  // 8-byte bf16 quad

// async global -> LDS, 16B per lane, wave-uniform LDS base (+lane*16)
__device__ inline void gload16(const void* g, void* l) {
  __builtin_amdgcn_global_load_lds(
      (const __attribute__((address_space(1))) void*)g,
      (__attribute__((address_space(3))) void*)l, 16, 0, 0);
}

// ---------------- decay vectors ----------------
__global__ void k_decay(float* __restrict__ decay, float* __restrict__ dbeta,
                        float* __restrict__ aL) {
  int h = blockIdx.x * blockDim.x + threadIdx.x;
  if (h >= kD) return;
  float kk = 2.0f + 6.0f * (float)h / (float)(kD - 1);
  float d = exp2f(-1.0f / kk);        // 0.5^(1/k)
  decay[h] = d;
  dbeta[h] = 1.0f - d;
  aL[h] = exp2f(-(float)kChunk / kk); // decay^CHUNK
}

// ---------------- block reduce (sum, sumsq) over 256 threads ---------------
__device__ inline void blockReduce2(float& s1, float& s2) {
#pragma unroll
  for (int off = 32; off > 0; off >>= 1) {
    s1 += __shfl_down(s1, off);
    s2 += __shfl_down(s2, off);
  }
  __shared__ float r1[4], r2[4];
  int wid = threadIdx.x >> 6;
  if ((threadIdx.x & 63) == 0) { r1[wid] = s1; r2[wid] = s2; }
  __syncthreads();
  s1 = r1[0] + r1[1] + r1[2] + r1[3];
  s2 = r2[0] + r2[1] + r2[2] + r2[3];
}

// ---------------- LayerNorm f32 -> bf16 (1 block = 1 row) -----------------
__global__ __launch_bounds__(256) void k_ln_f32in(
    const float* __restrict__ x, const float* __restrict__ w,
    const float* __restrict__ b, __hip_bfloat16* __restrict__ y) {
  int row = blockIdx.x;
  int t = threadIdx.x;
  const float4 v = reinterpret_cast<const float4*>(x + (size_t)row * kD)[t];
  float s1 = v.x + v.y + v.z + v.w;
  float s2 = v.x * v.x + v.y * v.y + v.z * v.z + v.w * v.w;
  blockReduce2(s1, s2);
  float mu = s1 * (1.0f / kD);
  float var = s2 * (1.0f / kD) - mu * mu;
  float rs = rsqrtf(var + kEps);
  float4 wv = reinterpret_cast<const float4*>(w)[t];
  float4 bv = reinterpret_cast<const float4*>(b)[t];
  bh4 o;
  o.a = __float2bfloat16((v.x - mu) * rs * wv.x + bv.x);
  o.b = __float2bfloat16((v.y - mu) * rs * wv.y + bv.y);
  o.c = __float2bfloat16((v.z - mu) * rs * wv.z + bv.z);
  o.d = __float2bfloat16((v.w - mu) * rs * wv.w + bv.w);
  reinterpret_cast<bh4*>(y + (size_t)row * kD)[t] = o;
}

// ---------------- LayerNorm bf16 -> bf16 (1 block = 1 row) ----------------
__global__ __launch_bounds__(256) void k_ln_bf16in(
    const __hip_bfloat16* __restrict__ x, const float* __restrict__ w,
    const float* __restrict__ b, __hip_bfloat16* __restrict__ y) {
  int row = blockIdx.x;
  int t = threadIdx.x;
  short4 q = reinterpret_cast<const short4*>(x + (size_t)row * kD)[t];
  float vv[4] = {bf2f(q.x), bf2f(q.y), bf2f(q.z), bf2f(q.w)};
  float s1 = vv[0] + vv[1] + vv[2] + vv[3];
  float s2 = vv[0] * vv[0] + vv[1] * vv[1] + vv[2] * vv[2] + vv[3] * vv[3];
  blockReduce2(s1, s2);
  float mu = s1 * (1.0f / kD);
  float var = s2 * (1.0f / kD) - mu * mu;
  float rs = rsqrtf(var + kEps);
  float4 wv = reinterpret_cast<const float4*>(w)[t];
  float4 bv = reinterpret_cast<const float4*>(b)[t];
  bh4 o;
  o.a = __float2bfloat16((vv[0] - mu) * rs * wv.x + bv.x);
  o.b = __float2bfloat16((vv[1] - mu) * rs * wv.y + bv.y);
  o.c = __float2bfloat16((vv[2] - mu) * rs * wv.z + bv.z);
  o.d = __float2bfloat16((vv[3] - mu) * rs * wv.w + bv.w);
  reinterpret_cast<bh4*>(y + (size_t)row * kD)[t] = o;
}

// ---------------- weight transpose-cast: W[K][1024] f32 -> WT[1024][K] bf16
__global__ __launch_bounds__(256) void k_transpose_cast(
    const float* __restrict__ W, __hip_bfloat16* __restrict__ WT, int K) {
  __shared__ float tile[32][33];
  int n0 = blockIdx.x * 32, k0 = blockIdx.y * 32;
  int t = threadIdx.x;
  int tr = t >> 3, tc4 = (t & 7) * 4;
  float4 v = *reinterpret_cast<const float4*>(W + (size_t)(k0 + tr) * kD + n0 + tc4);
  tile[tc4 + 0][tr] = v.x;
  tile[tc4 + 1][tr] = v.y;
  tile[tc4 + 2][tr] = v.z;
  tile[tc4 + 3][tr] = v.w;
  __syncthreads();
  bh4 o;
  o.a = __float2bfloat16(tile[tr][tc4 + 0]);
  o.b = __float2bfloat16(tile[tr][tc4 + 1]);
  o.c = __float2bfloat16(tile[tr][tc4 + 2]);
  o.d = __float2bfloat16(tile[tr][tc4 + 3]);
  *reinterpret_cast<bh4*>(WT + (size_t)(n0 + tr) * K + k0 + tc4) = o;
}

// MFMA cluster for phase Q (rows 2Q, 2Q+1 of the wave's 8 acc rows)
#define MFMA_PHASE(Q, AF)                                                    \
  do {                                                                       \
    __builtin_amdgcn_s_setprio(1);                                           \
    _Pragma("unroll") for (int mm = 0; mm < 2; ++mm)                         \
        _Pragma("unroll") for (int n = 0; n < 4; ++n)                        \
            _Pragma("unroll") for (int ks = 0; ks < 2; ++ks)                 \
                acc[2 * (Q) + mm][n] =                                       \
        __builtin_amdgcn_mfma_f32_16x16x32_bf16(AF[mm][ks], bfr[n][ks],      \
                                                acc[2 * (Q) + mm][n], 0, 0,  \
                                                0);                          \
    __builtin_amdgcn_s_setprio(0);                                           \
  } while (0)

// ---------------- bf16 MFMA GEMM, 256x256 tile, BK=64, 8 waves ------------
// Phase-pipelined (T3+T4): 4 phases per K-tile. Register-fragment ds_reads
// are issued ONE PHASE AHEAD of their consuming MFMA cluster (q0 reads
// B + A(q0) + A(q1); q1 reads A(q2); q2 reads A(q3)), so each phase's MFMA
// covers the next phase's LDS latency. No inline lgkmcnt/sched_barrier:
// ds_reads are compiler-visible, hipcc emits exact fine-grained lgkmcnt
// before each MFMA. Raw s_barriers carry asm("" ::: "memory") fences since
// the builtin alone is not a compiler memory fence. Counted vmcnt(4) only
// at q3 (never 0 in steady state). LDS k-major [kgrp8][row128][8bf16]:
// conflict-free (round-4/5 measured 0 conflicts) and linear for
// global_load_lds. Slot lifetimes identical to round-5 (race-free, passed):
// stageA(T+1) -> other buffer (readers drained before T-1 close);
// stageB(T+2) -> current buffer B slots (readers drained before q0 MFMA).
__global__ __launch_bounds__(512, 2) void k_mfma_gemm(
    const __hip_bfloat16* __restrict__ A1, const __hip_bfloat16* __restrict__ A2,
    const __hip_bfloat16* __restrict__ BT, int K,
    float* __restrict__ C, __hip_bfloat16* __restrict__ Cb,
    const float* __restrict__ colscale, const float* __restrict__ bias) {
  __shared__ short As[2][2][8192];  // [dbuf][half][kgrp*1024 + rh*512 + ...]
  __shared__ short Bs[2][2][8192];
  const int t = threadIdx.x;
  const int wid = t >> 6, lane = t & 63;
  // bijective XCD swizzle (nwg == 256, % 8 == 0)
  const int nwg = gridDim.x;
  const int bid = blockIdx.x;
  const int s = (bid & 7) * (nwg >> 3) + (bid >> 3);
  const int bn = (s & 3) * 256;   // 4 column tiles (kD/256)
  const int bm = (s >> 2) * 256;
  const int wr = wid >> 2;        // 0..1  (M dir; owns A half wr)
  const int wcn = wid & 3;        // 0..3  (N dir; reads B half wcn>>1)
  const int r = lane & 15, kg = lane >> 4;
  const int NT = K / 64;

  auto stageA = [&](int kt, int h) {
    const __hip_bfloat16* Asrc = A1;
    int kk = kt * 64;
    if (A2 && kk >= kD) { Asrc = A2; kk -= kD; }
    short* dst = &As[kt & 1][h][0];
#pragma unroll
    for (int j = 0; j < 2; ++j) {
      int row = j * 64 + lane;
      gload16(Asrc + (size_t)(bm + h * 128 + row) * kD + kk + wid * 8,
              dst + wid * 1024 + j * 512 + lane * 8);
    }
  };
  auto stageB = [&](int kt, int h) {
    short* dst = &Bs[kt & 1][h][0];
#pragma unroll
    for (int j = 0; j < 2; ++j) {
      int row = j * 64 + lane;
      gload16(BT + (size_t)(bn + h * 128 + row) * K + kt * 64 + wid * 8,
              dst + wid * 1024 + j * 512 + lane * 8);
    }
  };

  f32x4 acc[8][4];
#pragma unroll
  for (int m = 0; m < 8; ++m)
#pragma unroll
    for (int n = 0; n < 4; ++n) acc[m][n] = (f32x4){0.f, 0.f, 0.f, 0.f};

  // prologue: tile 0 fully + B halves of tile 1 (12 loads/wave)
  stageA(0, 0); stageA(0, 1); stageB(0, 0); stageB(0, 1);
  stageB(1, 0); stageB(1, 1);
  asm volatile("s_waitcnt vmcnt(4)" ::: "memory");  // tile 0 landed
  __builtin_amdgcn_s_barrier();
  asm volatile("" ::: "memory");

  for (int T = 0; T < NT; ++T) {
    const int bc = T & 1;
    const short* Ab = &As[bc][wr][0];
    const short* Bb = &Bs[bc][wcn >> 1][0];
    const int bcol = (wcn & 1) * 64;
    bf16x8 bfr[4][2];
    bf16x8 aX[2][2], aY[2][2];  // named (static-indexed) frag buffers
    auto rdA = [&](bf16x8 (&dst)[2][2], int q) {
#pragma unroll
      for (int mm = 0; mm < 2; ++mm)
#pragma unroll
        for (int ks = 0; ks < 2; ++ks)
          dst[mm][ks] = *reinterpret_cast<const bf16x8*>(
              Ab + (ks * 4 + kg) * 1024 + ((2 * q + mm) * 16 + r) * 8);
    };
    // ---- q0: read B(8) + A(q0)->aX + A(q1)->aY; stage A(T+1,0) ----
#pragma unroll
    for (int n = 0; n < 4; ++n)
#pragma unroll
      for (int ks = 0; ks < 2; ++ks)
        bfr[n][ks] = *reinterpret_cast<const bf16x8*>(
            Bb + (ks * 4 + kg) * 1024 + (bcol + n * 16 + r) * 8);
    rdA(aX, 0);
    rdA(aY, 1);
    if (T + 1 < NT) stageA(T + 1, 0);
    asm volatile("" ::: "memory");
    __builtin_amdgcn_s_barrier();
    asm volatile("" ::: "memory");
    MFMA_PHASE(0, aX);
    asm volatile("" ::: "memory");
    __builtin_amdgcn_s_barrier();
    asm volatile("" ::: "memory");
    // ---- q1: read A(q2)->aX; stage A(T+1,1); MFMA consumes aY ----
    rdA(aX, 2);
    if (T + 1 < NT) stageA(T + 1, 1);
    asm volatile("" ::: "memory");
    __builtin_amdgcn_s_barrier();
    asm volatile("" ::: "memory");
    MFMA_PHASE(1, aY);
    asm volatile("" ::: "memory");
    __builtin_amdgcn_s_barrier();
    asm volatile("" ::: "memory");
    // ---- q2: read A(q3)->aY; stage B(T+2,0); MFMA consumes aX ----
    rdA(aY, 3);
    if (T + 2 < NT) stageB(T + 2, 0);
    asm volatile("" ::: "memory");
    __builtin_amdgcn_s_barrier();
    asm volatile("" ::: "memory");
    MFMA_PHASE(2, aX);
    asm volatile("" ::: "memory");
    __builtin_amdgcn_s_barrier();
    asm volatile("" ::: "memory");
    // ---- q3: stage B(T+2,1); MFMA consumes aY; counted vmcnt; handshake ----
    if (T + 2 < NT) stageB(T + 2, 1);
    asm volatile("" ::: "memory");
    __builtin_amdgcn_s_barrier();
    asm volatile("" ::: "memory");
    MFMA_PHASE(3, aY);
    if (T + 1 < NT) {
      if (T + 2 < NT)
        asm volatile("s_waitcnt vmcnt(4)" ::: "memory");  // tile T+1 landed
      else
        asm volatile("s_waitcnt vmcnt(0)" ::: "memory");
    }
    asm volatile("" ::: "memory");
    __builtin_amdgcn_s_barrier();
    asm volatile("" ::: "memory");
  }

  // epilogue: D[row = kg*4+j][col = r] per fragment (m89-verified mapping)
  int col[4];
  float cs[4], bi[4];
#pragma unroll
  for (int n = 0; n < 4; ++n) {
    col[n] = bn + wcn * 64 + n * 16 + r;
    cs[n] = colscale ? colscale[col[n]] : 1.0f;
    bi[n] = bias ? bias[col[n]] : 0.0f;
  }
#pragma unroll
  for (int m = 0; m < 8; ++m) {
#pragma unroll
    for (int j = 0; j < 4; ++j) {
      int row = bm + wr * 128 + m * 16 + kg * 4 + j;
#pragma unroll
      for (int n = 0; n < 4; ++n) {
        float v = acc[m][n][j] * cs[n] + bi[n];
        if (C) C[(size_t)row * kD + col[n]] = v;
        if (Cb) Cb[(size_t)row * kD + col[n]] = __float2bfloat16(v);
      }
    }
  }
}

// ---------------- chunked scan, phase 1: per-chunk end values (bf16 in) ---
__global__ __launch_bounds__(256) void k_scan_ends(
    const __hip_bfloat16* __restrict__ u, const float* __restrict__ decay,
    float* __restrict__ ends) {
  int tid = blockIdx.x * blockDim.x + threadIdx.x;  // [0, B*NCHUNK*D)
  int h = tid & (kD - 1);
  int c = (tid >> 10) & (kNChunk - 1);
  int b = tid >> 14;
  float a = decay[h];
  const __hip_bfloat16* up =
      u + ((size_t)(b * kS) + (size_t)c * kChunk) * kD + h;
  float v = 0.f;
#pragma unroll 8
  for (int i = 0; i < kChunk; ++i)
    v = fmaf(a, v, bf2f(*(const short*)(up + (size_t)i * kD)));
  ends[tid] = v;
}

// ---------------- phase 2: scan carries across chunks ---------------------
__global__ __launch_bounds__(256) void k_scan_carry(
    const float* __restrict__ ends, const float* __restrict__ aL,
    float* __restrict__ carry) {
  int tid = blockIdx.x * blockDim.x + threadIdx.x;  // [0, B*D)
  int h = tid & (kD - 1);
  int b = tid >> 10;
  float al = aL[h];
  float car = 0.f;
#pragma unroll
  for (int c = 0; c < kNChunk; ++c) {
    size_t idx = ((size_t)(b * kNChunk + c)) * kD + h;
    carry[idx] = car;
    car = fmaf(al, car, ends[idx]);
  }
}

// ---------------- phase 3: rescan with carry, in-place u -> cx (bf16) -----
__global__ __launch_bounds__(256) void k_scan_apply(
    __hip_bfloat16* __restrict__ u, const float* __restrict__ decay,
    const float* __restrict__ carry) {
  int tid = blockIdx.x * blockDim.x + threadIdx.x;
  int h = tid & (kD - 1);
  int c = (tid >> 10) & (kNChunk - 1);
  int b = tid >> 14;
  float a = decay[h];
  float v = carry[tid];
  __hip_bfloat16* up = u + ((size_t)(b * kS) + (size_t)c * kChunk) * kD + h;
#pragma unroll 8
  for (int i = 0; i < kChunk; ++i) {
    v = fmaf(a, v, bf2f(*(const short*)(up + (size_t)i * kD)));
    up[(size_t)i * kD] = __float2bfloat16(v);
  }
}

// ---------------- final: LN(gpre) -> sigmoid -> blend ---------------------
__global__ __launch_bounds__(256) void k_final(
    const __hip_bfloat16* __restrict__ gpre, const __hip_bfloat16* __restrict__ res,
    const __hip_bfloat16* __restrict__ outp, const float* __restrict__ w,
    const float* __restrict__ b, float* __restrict__ y) {
  int row = blockIdx.x;
  int t = threadIdx.x;
  short4 q = reinterpret_cast<const short4*>(gpre + (size_t)row * kD)[t];
  float vv[4] = {bf2f(q.x), bf2f(q.y), bf2f(q.z), bf2f(q.w)};
  float s1 = vv[0] + vv[1] + vv[2] + vv[3];
  float s2 = vv[0] * vv[0] + vv[1] * vv[1] + vv[2] * vv[2] + vv[3] * vv[3];
  blockReduce2(s1, s2);
  float mu = s1 * (1.0f / kD);
  float var = s2 * (1.0f / kD) - mu * mu;
  float rs = rsqrtf(var + kEps);
  float4 wv = reinterpret_cast<const float4*>(w)[t];
  float4 bv = reinterpret_cast<const float4*>(b)[t];
  short4 r4 = reinterpret_cast<const short4*>(res + (size_t)row * kD)[t];
  short4 o4 = reinterpret_cast<const short4*>(outp + (size_t)row * kD)[t];
  float rr[4] = {bf2f(r4.x), bf2f(r4.y), bf2f(r4.z), bf2f(r4.w)};
  float oo[4] = {bf2f(o4.x), bf2f(o4.y), bf2f(o4.z), bf2f(o4.w)};
  float ww[4] = {wv.x, wv.y, wv.z, wv.w};
  float bb[4] = {bv.x, bv.y, bv.z, bv.w};
  float4 out;
  float* op = &out.x;
#pragma unroll
  for (int i = 0; i < 4; ++i) {
    float z = (vv[i] - mu) * rs * ww[i] + bb[i];
    float g = 1.0f / (1.0f + expf(-z));
    op[i] = rr[i] + g * (oo[i] - rr[i]);
  }
  reinterpret_cast<float4*>(y + (size_t)row * kD)[t] = out;
}

}  // namespace

extern "C" void kernel_launch(void* const* d_in, const int* in_sizes, int n_in,
                              void* d_out, int out_size, void* d_ws,
                              size_t ws_size, hipStream_t stream) {
  const float* x = (const float*)d_in[0];
  const float* Wt = (const float*)d_in[1];
  const float* Wo = (const float*)d_in[2];
  const float* Wg = (const float*)d_in[3];
  const float* bg = (const float*)d_in[4];
  const float* ln1w = (const float*)d_in[5];
  const float* ln1b = (const float*)d_in[6];
  const float* lncw = (const float*)d_in[7];
  const float* lncb = (const float*)d_in[8];
  const float* lngw = (const float*)d_in[9];
  const float* lngb = (const float*)d_in[10];
  float* y = (float*)d_out;

  char* ws = (char*)d_ws;
  size_t off = 0;
  auto alloc = [&](size_t bytes) {
    char* p = ws + off;
    off += (bytes + 255) & ~(size_t)255;
    return p;
  };
  __hip_bfloat16* xnb = (__hip_bfloat16*)alloc((size_t)kN * kD * 2);  // _x (res)
  __hip_bfloat16* ub = (__hip_bfloat16*)alloc((size_t)kN * kD * 2);   // u -> cx -> gpre
  __hip_bfloat16* outb = (__hip_bfloat16*)alloc((size_t)kN * kD * 2); // out
  __hip_bfloat16* cxn = (__hip_bfloat16*)alloc((size_t)kN * kD * 2);  // LN(cx)
  __hip_bfloat16* WtT = (__hip_bfloat16*)alloc((size_t)kD * kD * 2);
  __hip_bfloat16* WoT = (__hip_bfloat16*)alloc((size_t)kD * kD * 2);
  __hip_bfloat16* WgT = (__hip_bfloat16*)alloc((size_t)kD * 2 * kD * 2);
  float* decay = (float*)alloc(kD * 4);
  float* dbeta = (float*)alloc(kD * 4);
  float* aL = (float*)alloc(kD * 4);
  float* ends = (float*)alloc((size_t)kB * kNChunk * kD * 4);
  float* carry = (float*)alloc((size_t)kB * kNChunk * kD * 4);

  const int nwg = (kD / 256) * (kN / 256);  // 4 * 64 = 256, % 8 == 0

  k_decay<<<(kD + 255) / 256, 256, 0, stream>>>(decay, dbeta, aL);
  // weight transpose-casts (f32 [K][N] -> bf16 [N][K])
  k_transpose_cast<<<dim3(kD / 32, kD / 32), 256, 0, stream>>>(Wt, WtT, kD);
  k_transpose_cast<<<dim3(kD / 32, kD / 32), 256, 0, stream>>>(Wo, WoT, kD);
  k_transpose_cast<<<dim3(kD / 32, 2 * kD / 32), 256, 0, stream>>>(Wg, WgT, 2 * kD);
  // _x = LN(x) -> bf16
  k_ln_f32in<<<kN, 256, 0, stream>>>(x, ln1w, ln1b, xnb);
  // u = (_x @ Wt) * decay_beta   (bf16 out)
  k_mfma_gemm<<<nwg, 512, 0, stream>>>(xnb, nullptr, WtT, kD, nullptr, ub,
                                       dbeta, nullptr);
  // chunked scan: u -> cx (in place, bf16 storage, f32 accumulate)
  k_scan_ends<<<(kB * kNChunk * kD) / 256, 256, 0, stream>>>(ub, decay, ends);
  k_scan_carry<<<(kB * kD) / 256, 256, 0, stream>>>(ends, aL, carry);
  k_scan_apply<<<(kB * kNChunk * kD) / 256, 256, 0, stream>>>(ub, decay, carry);
  // cxn = LN(cx) -> bf16
  k_ln_bf16in<<<kN, 256, 0, stream>>>(ub, lncw, lncb, cxn);
  // out = LN(cx) @ Wo  (bf16 out)
  k_mfma_gemm<<<nwg, 512, 0, stream>>>(cxn, nullptr, WoT, kD, nullptr, outb,
                                       nullptr, nullptr);
  // gpre = concat(_x, out) @ Wg + bg  (bf16 out, overwrites ub; cx dead)
  k_mfma_gemm<<<nwg, 512, 0, stream>>>(xnb, outb, WgT, 2 * kD, nullptr, ub,
                                       nullptr, bg);
  // y = res + sigmoid(LN(gpre)) * (out - res)
  k_final<<<kN, 256, 0, stream>>>(ub, xnb, outb, lngw, lngb, y);
}

// Round 7
// 276.437 us; speedup vs baseline: 1.4708x; 1.0069x over previous
//
#include <hip/hip_runtime.h>
#include <hip/hip_bf16.h>
#include <cmath>
#include <cstdint>

namespace {

constexpr int kB = 8;
constexpr int kS = 2048;
constexpr int kD = 1024;
constexpr int kN = kB * kS;          // 16384 rows
constexpr int kChunk = 128;
constexpr int kNChunk = kS / kChunk; // 16
constexpr float kEps = 1e-6f;

typedef __attribute__((ext_vector_type(8))) short bf16x8;
typedef __attribute__((ext_vector_type(4))) float f32x4;

__device__ inline float bf2f(short s) {
  union { unsigned u; float f; } c;
  c.u = ((unsigned)(unsigned short)s) << 16;
  return c.f;
}

struct bh4 { __hip_bfloat16 a, b, c, d; };  // 8-byte bf16 quad

// async global -> LDS, 16B per lane, wave-uniform LDS base (+lane*16)
__device__ inline void gload16(const void* g, void* l) {
  __builtin_amdgcn_global_load_lds(
      (const __attribute__((address_space(1))) void*)g,
      (__attribute__((address_space(3))) void*)l, 16, 0, 0);
}

// ---------------- decay vectors ----------------
__global__ void k_decay(float* __restrict__ decay, float* __restrict__ dbeta,
                        float* __restrict__ aL) {
  int h = blockIdx.x * blockDim.x + threadIdx.x;
  if (h >= kD) return;
  float kk = 2.0f + 6.0f * (float)h / (float)(kD - 1);
  float d = exp2f(-1.0f / kk);        // 0.5^(1/k)
  decay[h] = d;
  dbeta[h] = 1.0f - d;
  aL[h] = exp2f(-(float)kChunk / kk); // decay^CHUNK
}

// ---------------- block reduce (sum, sumsq) over 256 threads ---------------
__device__ inline void blockReduce2(float& s1, float& s2) {
#pragma unroll
  for (int off = 32; off > 0; off >>= 1) {
    s1 += __shfl_down(s1, off);
    s2 += __shfl_down(s2, off);
  }
  __shared__ float r1[4], r2[4];
  int wid = threadIdx.x >> 6;
  if ((threadIdx.x & 63) == 0) { r1[wid] = s1; r2[wid] = s2; }
  __syncthreads();
  s1 = r1[0] + r1[1] + r1[2] + r1[3];
  s2 = r2[0] + r2[1] + r2[2] + r2[3];
}

// ---------------- LayerNorm f32 -> bf16 (1 block = 1 row) -----------------
__global__ __launch_bounds__(256) void k_ln_f32in(
    const float* __restrict__ x, const float* __restrict__ w,
    const float* __restrict__ b, __hip_bfloat16* __restrict__ y) {
  int row = blockIdx.x;
  int t = threadIdx.x;
  const float4 v = reinterpret_cast<const float4*>(x + (size_t)row * kD)[t];
  float s1 = v.x + v.y + v.z + v.w;
  float s2 = v.x * v.x + v.y * v.y + v.z * v.z + v.w * v.w;
  blockReduce2(s1, s2);
  float mu = s1 * (1.0f / kD);
  float var = s2 * (1.0f / kD) - mu * mu;
  float rs = rsqrtf(var + kEps);
  float4 wv = reinterpret_cast<const float4*>(w)[t];
  float4 bv = reinterpret_cast<const float4*>(b)[t];
  bh4 o;
  o.a = __float2bfloat16((v.x - mu) * rs * wv.x + bv.x);
  o.b = __float2bfloat16((v.y - mu) * rs * wv.y + bv.y);
  o.c = __float2bfloat16((v.z - mu) * rs * wv.z + bv.z);
  o.d = __float2bfloat16((v.w - mu) * rs * wv.w + bv.w);
  reinterpret_cast<bh4*>(y + (size_t)row * kD)[t] = o;
}

// ---------------- LayerNorm bf16 -> bf16 (1 block = 1 row) ----------------
__global__ __launch_bounds__(256) void k_ln_bf16in(
    const __hip_bfloat16* __restrict__ x, const float* __restrict__ w,
    const float* __restrict__ b, __hip_bfloat16* __restrict__ y) {
  int row = blockIdx.x;
  int t = threadIdx.x;
  short4 q = reinterpret_cast<const short4*>(x + (size_t)row * kD)[t];
  float vv[4] = {bf2f(q.x), bf2f(q.y), bf2f(q.z), bf2f(q.w)};
  float s1 = vv[0] + vv[1] + vv[2] + vv[3];
  float s2 = vv[0] * vv[0] + vv[1] * vv[1] + vv[2] * vv[2] + vv[3] * vv[3];
  blockReduce2(s1, s2);
  float mu = s1 * (1.0f / kD);
  float var = s2 * (1.0f / kD) - mu * mu;
  float rs = rsqrtf(var + kEps);
  float4 wv = reinterpret_cast<const float4*>(w)[t];
  float4 bv = reinterpret_cast<const float4*>(b)[t];
  bh4 o;
  o.a = __float2bfloat16((vv[0] - mu) * rs * wv.x + bv.x);
  o.b = __float2bfloat16((vv[1] - mu) * rs * wv.y + bv.y);
  o.c = __float2bfloat16((vv[2] - mu) * rs * wv.z + bv.z);
  o.d = __float2bfloat16((vv[3] - mu) * rs * wv.w + bv.w);
  reinterpret_cast<bh4*>(y + (size_t)row * kD)[t] = o;
}

// ---------------- weight transpose-cast: W[K][1024] f32 -> WT[1024][K] bf16
__global__ __launch_bounds__(256) void k_transpose_cast(
    const float* __restrict__ W, __hip_bfloat16* __restrict__ WT, int K) {
  __shared__ float tile[32][33];
  int n0 = blockIdx.x * 32, k0 = blockIdx.y * 32;
  int t = threadIdx.x;
  int tr = t >> 3, tc4 = (t & 7) * 4;
  float4 v = *reinterpret_cast<const float4*>(W + (size_t)(k0 + tr) * kD + n0 + tc4);
  tile[tc4 + 0][tr] = v.x;
  tile[tc4 + 1][tr] = v.y;
  tile[tc4 + 2][tr] = v.z;
  tile[tc4 + 3][tr] = v.w;
  __syncthreads();
  bh4 o;
  o.a = __float2bfloat16(tile[tr][tc4 + 0]);
  o.b = __float2bfloat16(tile[tr][tc4 + 1]);
  o.c = __float2bfloat16(tile[tr][tc4 + 2]);
  o.d = __float2bfloat16(tile[tr][tc4 + 3]);
  *reinterpret_cast<bh4*>(WT + (size_t)(n0 + tr) * K + k0 + tc4) = o;
}

// ---------------- bf16 MFMA GEMM, 256x256 tile, BK=64, 8 waves ------------
// 2 phases per K-tile (4 barriers, halved sync overhead vs 4-phase):
//  phase A: read B-frags(8) + A-low(16) b128 -> stage A(T+1) (4 gloads)
//           -> barrier -> 32 MFMA (acc rows 0..3) -> barrier
//  phase B: read A-high(8) -> stage B(T+2) (4 gloads)
//           -> barrier -> 32 MFMA (acc rows 4..7) -> vmcnt(4) -> barrier
// Counted vmcnt once per K-tile, never 0 in steady state (T4): at the wait,
// A(T+1) has landed, B(T+2) stays in flight. Compiler places fine-grained
// lgkmcnt between ds_reads and MFMAs (no manual lgkm/sched_barrier -- m141
// lesson). Raw s_barriers carry asm("" ::: "memory") compiler fences.
// LDS k-major [kgrp8][row128][8bf16] per half-tile: conflict-free (rounds
// 4-6 measured 0 conflicts) and linear for global_load_lds (rule #21).
// Slot lifetimes (race-free, passed r5/r6): stageA(T+1) -> other buffer,
// readers drained before tile T-1's closing barrier; stageB(T+2) -> current
// buffer B slots, readers (bfr) retired before phase A's closing barrier.
__global__ __launch_bounds__(512, 2) void k_mfma_gemm(
    const __hip_bfloat16* __restrict__ A1, const __hip_bfloat16* __restrict__ A2,
    const __hip_bfloat16* __restrict__ BT, int K,
    float* __restrict__ C, __hip_bfloat16* __restrict__ Cb,
    const float* __restrict__ colscale, const float* __restrict__ bias) {
  __shared__ short As[2][2][8192];  // [dbuf][half][kgrp*1024 + rh*512 + ...]
  __shared__ short Bs[2][2][8192];
  const int t = threadIdx.x;
  const int wid = t >> 6, lane = t & 63;
  // bijective XCD swizzle (nwg == 256, % 8 == 0)
  const int nwg = gridDim.x;
  const int bid = blockIdx.x;
  const int s = (bid & 7) * (nwg >> 3) + (bid >> 3);
  const int bn = (s & 3) * 256;   // 4 column tiles (kD/256)
  const int bm = (s >> 2) * 256;
  const int wr = wid >> 2;        // 0..1  (M dir; owns A half wr)
  const int wcn = wid & 3;        // 0..3  (N dir; reads B half wcn>>1)
  const int r = lane & 15, kg = lane >> 4;
  const int NT = K / 64;

  auto stageA = [&](int kt, int h) {
    const __hip_bfloat16* Asrc = A1;
    int kk = kt * 64;
    if (A2 && kk >= kD) { Asrc = A2; kk -= kD; }
    short* dst = &As[kt & 1][h][0];
#pragma unroll
    for (int j = 0; j < 2; ++j) {
      int row = j * 64 + lane;
      gload16(Asrc + (size_t)(bm + h * 128 + row) * kD + kk + wid * 8,
              dst + wid * 1024 + j * 512 + lane * 8);
    }
  };
  auto stageB = [&](int kt, int h) {
    short* dst = &Bs[kt & 1][h][0];
#pragma unroll
    for (int j = 0; j < 2; ++j) {
      int row = j * 64 + lane;
      gload16(BT + (size_t)(bn + h * 128 + row) * K + kt * 64 + wid * 8,
              dst + wid * 1024 + j * 512 + lane * 8);
    }
  };

  f32x4 acc[8][4];
#pragma unroll
  for (int m = 0; m < 8; ++m)
#pragma unroll
    for (int n = 0; n < 4; ++n) acc[m][n] = (f32x4){0.f, 0.f, 0.f, 0.f};

  // prologue: tile 0 fully + B of tile 1 (12 loads/wave); wait tile 0 only
  stageA(0, 0); stageA(0, 1); stageB(0, 0); stageB(0, 1);
  stageB(1, 0); stageB(1, 1);
  asm volatile("s_waitcnt vmcnt(4)" ::: "memory");  // tile 0 landed
  __builtin_amdgcn_s_barrier();
  asm volatile("" ::: "memory");

  for (int T = 0; T < NT; ++T) {
    const int bc = T & 1;
    const short* Ab = &As[bc][wr][0];
    const short* Bb = &Bs[bc][wcn >> 1][0];
    const int bcol = (wcn & 1) * 64;
    bf16x8 bfr[4][2], aLO[4][2], aHI[4][2];
    // ================= phase A =================
#pragma unroll
    for (int n = 0; n < 4; ++n)
#pragma unroll
      for (int ks = 0; ks < 2; ++ks)
        bfr[n][ks] = *reinterpret_cast<const bf16x8*>(
            Bb + (ks * 4 + kg) * 1024 + (bcol + n * 16 + r) * 8);
#pragma unroll
    for (int mm = 0; mm < 4; ++mm)
#pragma unroll
      for (int ks = 0; ks < 2; ++ks)
        aLO[mm][ks] = *reinterpret_cast<const bf16x8*>(
            Ab + (ks * 4 + kg) * 1024 + (mm * 16 + r) * 8);
    if (T + 1 < NT) { stageA(T + 1, 0); stageA(T + 1, 1); }
    asm volatile("" ::: "memory");
    __builtin_amdgcn_s_barrier();
    asm volatile("" ::: "memory");
    __builtin_amdgcn_s_setprio(1);
#pragma unroll
    for (int mm = 0; mm < 4; ++mm)
#pragma unroll
      for (int n = 0; n < 4; ++n)
#pragma unroll
        for (int ks = 0; ks < 2; ++ks)
          acc[mm][n] = __builtin_amdgcn_mfma_f32_16x16x32_bf16(
              aLO[mm][ks], bfr[n][ks], acc[mm][n], 0, 0, 0);
    __builtin_amdgcn_s_setprio(0);
    asm volatile("" ::: "memory");
    __builtin_amdgcn_s_barrier();
    asm volatile("" ::: "memory");
    // ================= phase B =================
#pragma unroll
    for (int mm = 0; mm < 4; ++mm)
#pragma unroll
      for (int ks = 0; ks < 2; ++ks)
        aHI[mm][ks] = *reinterpret_cast<const bf16x8*>(
            Ab + (ks * 4 + kg) * 1024 + ((mm + 4) * 16 + r) * 8);
    if (T + 2 < NT) { stageB(T + 2, 0); stageB(T + 2, 1); }
    asm volatile("" ::: "memory");
    __builtin_amdgcn_s_barrier();
    asm volatile("" ::: "memory");
    __builtin_amdgcn_s_setprio(1);
#pragma unroll
    for (int mm = 0; mm < 4; ++mm)
#pragma unroll
      for (int n = 0; n < 4; ++n)
#pragma unroll
        for (int ks = 0; ks < 2; ++ks)
          acc[mm + 4][n] = __builtin_amdgcn_mfma_f32_16x16x32_bf16(
              aHI[mm][ks], bfr[n][ks], acc[mm + 4][n], 0, 0, 0);
    __builtin_amdgcn_s_setprio(0);
    if (T + 2 < NT)
      asm volatile("s_waitcnt vmcnt(4)" ::: "memory");  // A(T+1) landed
    else if (T + 1 < NT)
      asm volatile("s_waitcnt vmcnt(0)" ::: "memory");  // last prefetch
    asm volatile("" ::: "memory");
    __builtin_amdgcn_s_barrier();
    asm volatile("" ::: "memory");
  }

  // epilogue: D[row = kg*4+j][col = r] per fragment (m89-verified mapping)
  int col[4];
  float cs[4], bi[4];
#pragma unroll
  for (int n = 0; n < 4; ++n) {
    col[n] = bn + wcn * 64 + n * 16 + r;
    cs[n] = colscale ? colscale[col[n]] : 1.0f;
    bi[n] = bias ? bias[col[n]] : 0.0f;
  }
#pragma unroll
  for (int m = 0; m < 8; ++m) {
#pragma unroll
    for (int j = 0; j < 4; ++j) {
      int row = bm + wr * 128 + m * 16 + kg * 4 + j;
#pragma unroll
      for (int n = 0; n < 4; ++n) {
        float v = acc[m][n][j] * cs[n] + bi[n];
        if (C) C[(size_t)row * kD + col[n]] = v;
        if (Cb) Cb[(size_t)row * kD + col[n]] = __float2bfloat16(v);
      }
    }
  }
}

// ---------------- chunked scan, phase 1: per-chunk end values (bf16 in) ---
__global__ __launch_bounds__(256) void k_scan_ends(
    const __hip_bfloat16* __restrict__ u, const float* __restrict__ decay,
    float* __restrict__ ends) {
  int tid = blockIdx.x * blockDim.x + threadIdx.x;  // [0, B*NCHUNK*D)
  int h = tid & (kD - 1);
  int c = (tid >> 10) & (kNChunk - 1);
  int b = tid >> 14;
  float a = decay[h];
  const __hip_bfloat16* up =
      u + ((size_t)(b * kS) + (size_t)c * kChunk) * kD + h;
  float v = 0.f;
#pragma unroll 8
  for (int i = 0; i < kChunk; ++i)
    v = fmaf(a, v, bf2f(*(const short*)(up + (size_t)i * kD)));
  ends[tid] = v;
}

// ---------------- phase 2: scan carries across chunks ---------------------
__global__ __launch_bounds__(256) void k_scan_carry(
    const float* __restrict__ ends, const float* __restrict__ aL,
    float* __restrict__ carry) {
  int tid = blockIdx.x * blockDim.x + threadIdx.x;  // [0, B*D)
  int h = tid & (kD - 1);
  int b = tid >> 10;
  float al = aL[h];
  float car = 0.f;
#pragma unroll
  for (int c = 0; c < kNChunk; ++c) {
    size_t idx = ((size_t)(b * kNChunk + c)) * kD + h;
    carry[idx] = car;
    car = fmaf(al, car, ends[idx]);
  }
}

// ---------------- phase 3: rescan with carry, in-place u -> cx (bf16) -----
__global__ __launch_bounds__(256) void k_scan_apply(
    __hip_bfloat16* __restrict__ u, const float* __restrict__ decay,
    const float* __restrict__ carry) {
  int tid = blockIdx.x * blockDim.x + threadIdx.x;
  int h = tid & (kD - 1);
  int c = (tid >> 10) & (kNChunk - 1);
  int b = tid >> 14;
  float a = decay[h];
  float v = carry[tid];
  __hip_bfloat16* up = u + ((size_t)(b * kS) + (size_t)c * kChunk) * kD + h;
#pragma unroll 8
  for (int i = 0; i < kChunk; ++i) {
    v = fmaf(a, v, bf2f(*(const short*)(up + (size_t)i * kD)));
    up[(size_t)i * kD] = __float2bfloat16(v);
  }
}

// ---------------- final: LN(gpre) -> sigmoid -> blend ---------------------
__global__ __launch_bounds__(256) void k_final(
    const __hip_bfloat16* __restrict__ gpre, const __hip_bfloat16* __restrict__ res,
    const __hip_bfloat16* __restrict__ outp, const float* __restrict__ w,
    const float* __restrict__ b, float* __restrict__ y) {
  int row = blockIdx.x;
  int t = threadIdx.x;
  short4 q = reinterpret_cast<const short4*>(gpre + (size_t)row * kD)[t];
  float vv[4] = {bf2f(q.x), bf2f(q.y), bf2f(q.z), bf2f(q.w)};
  float s1 = vv[0] + vv[1] + vv[2] + vv[3];
  float s2 = vv[0] * vv[0] + vv[1] * vv[1] + vv[2] * vv[2] + vv[3] * vv[3];
  blockReduce2(s1, s2);
  float mu = s1 * (1.0f / kD);
  float var = s2 * (1.0f / kD) - mu * mu;
  float rs = rsqrtf(var + kEps);
  float4 wv = reinterpret_cast<const float4*>(w)[t];
  float4 bv = reinterpret_cast<const float4*>(b)[t];
  short4 r4 = reinterpret_cast<const short4*>(res + (size_t)row * kD)[t];
  short4 o4 = reinterpret_cast<const short4*>(outp + (size_t)row * kD)[t];
  float rr[4] = {bf2f(r4.x), bf2f(r4.y), bf2f(r4.z), bf2f(r4.w)};
  float oo[4] = {bf2f(o4.x), bf2f(o4.y), bf2f(o4.z), bf2f(o4.w)};
  float ww[4] = {wv.x, wv.y, wv.z, wv.w};
  float bb[4] = {bv.x, bv.y, bv.z, bv.w};
  float4 out;
  float* op = &out.x;
#pragma unroll
  for (int i = 0; i < 4; ++i) {
    float z = (vv[i] - mu) * rs * ww[i] + bb[i];
    float g = 1.0f / (1.0f + expf(-z));
    op[i] = rr[i] + g * (oo[i] - rr[i]);
  }
  reinterpret_cast<float4*>(y + (size_t)row * kD)[t] = out;
}

}  // namespace

extern "C" void kernel_launch(void* const* d_in, const int* in_sizes, int n_in,
                              void* d_out, int out_size, void* d_ws,
                              size_t ws_size, hipStream_t stream) {
  const float* x = (const float*)d_in[0];
  const float* Wt = (const float*)d_in[1];
  const float* Wo = (const float*)d_in[2];
  const float* Wg = (const float*)d_in[3];
  const float* bg = (const float*)d_in[4];
  const float* ln1w = (const float*)d_in[5];
  const float* ln1b = (const float*)d_in[6];
  const float* lncw = (const float*)d_in[7];
  const float* lncb = (const float*)d_in[8];
  const float* lngw = (const float*)d_in[9];
  const float* lngb = (const float*)d_in[10];
  float* y = (float*)d_out;

  char* ws = (char*)d_ws;
  size_t off = 0;
  auto alloc = [&](size_t bytes) {
    char* p = ws + off;
    off += (bytes + 255) & ~(size_t)255;
    return p;
  };
  __hip_bfloat16* xnb = (__hip_bfloat16*)alloc((size_t)kN * kD * 2);  // _x (res)
  __hip_bfloat16* ub = (__hip_bfloat16*)alloc((size_t)kN * kD * 2);   // u -> cx -> gpre
  __hip_bfloat16* outb = (__hip_bfloat16*)alloc((size_t)kN * kD * 2); // out
  __hip_bfloat16* cxn = (__hip_bfloat16*)alloc((size_t)kN * kD * 2);  // LN(cx)
  __hip_bfloat16* WtT = (__hip_bfloat16*)alloc((size_t)kD * kD * 2);
  __hip_bfloat16* WoT = (__hip_bfloat16*)alloc((size_t)kD * kD * 2);
  __hip_bfloat16* WgT = (__hip_bfloat16*)alloc((size_t)kD * 2 * kD * 2);
  float* decay = (float*)alloc(kD * 4);
  float* dbeta = (float*)alloc(kD * 4);
  float* aL = (float*)alloc(kD * 4);
  float* ends = (float*)alloc((size_t)kB * kNChunk * kD * 4);
  float* carry = (float*)alloc((size_t)kB * kNChunk * kD * 4);

  const int nwg = (kD / 256) * (kN / 256);  // 4 * 64 = 256, % 8 == 0

  k_decay<<<(kD + 255) / 256, 256, 0, stream>>>(decay, dbeta, aL);
  // weight transpose-casts (f32 [K][N] -> bf16 [N][K])
  k_transpose_cast<<<dim3(kD / 32, kD / 32), 256, 0, stream>>>(Wt, WtT, kD);
  k_transpose_cast<<<dim3(kD / 32, kD / 32), 256, 0, stream>>>(Wo, WoT, kD);
  k_transpose_cast<<<dim3(kD / 32, 2 * kD / 32), 256, 0, stream>>>(Wg, WgT, 2 * kD);
  // _x = LN(x) -> bf16
  k_ln_f32in<<<kN, 256, 0, stream>>>(x, ln1w, ln1b, xnb);
  // u = (_x @ Wt) * decay_beta   (bf16 out)
  k_mfma_gemm<<<nwg, 512, 0, stream>>>(xnb, nullptr, WtT, kD, nullptr, ub,
                                       dbeta, nullptr);
  // chunked scan: u -> cx (in place, bf16 storage, f32 accumulate)
  k_scan_ends<<<(kB * kNChunk * kD) / 256, 256, 0, stream>>>(ub, decay, ends);
  k_scan_carry<<<(kB * kD) / 256, 256, 0, stream>>>(ends, aL, carry);
  k_scan_apply<<<(kB * kNChunk * kD) / 256, 256, 0, stream>>>(ub, decay, carry);
  // cxn = LN(cx) -> bf16
  k_ln_bf16in<<<kN, 256, 0, stream>>>(ub, lncw, lncb, cxn);
  // out = LN(cx) @ Wo  (bf16 out)
  k_mfma_gemm<<<nwg, 512, 0, stream>>>(cxn, nullptr, WoT, kD, nullptr, outb,
                                       nullptr, nullptr);
  // gpre = concat(_x, out) @ Wg + bg  (bf16 out, overwrites ub; cx dead)
  k_mfma_gemm<<<nwg, 512, 0, stream>>>(xnb, outb, WgT, 2 * kD, nullptr, ub,
                                       nullptr, bg);
  // y = res + sigmoid(LN(gpre)) * (out - res)
  k_final<<<kN, 256, 0, stream>>>(ub, xnb, outb, lngw, lngb, y);
}